// Round 1
// baseline (4644.446 us; speedup 1.0000x reference)
//
#include <hip/hip_runtime.h>
#include <hip/hip_bf16.h>

#define BB 4
#define NP 8192
#define SS 2048
#define KK 16
#define DD 64
#define NN (BB*SS*KK) // 131072

// ---------------- FPS: one block per batch, bit-exact vs numpy ----------------
__global__ __launch_bounds__(1024) void fps_kernel(
    const float* __restrict__ xyz, float* __restrict__ newXyz,
    float* __restrict__ out)
{
  const int b = blockIdx.x;
  const int t = threadIdx.x;
  const float* xb = xyz + (size_t)b * 3 * NP;
  float px[8], py[8], pz[8], dist[8];
#pragma unroll
  for (int j = 0; j < 8; j++) {
    int i = t + (j << 10);
    px[j] = xb[i]; py[j] = xb[NP + i]; pz[j] = xb[2 * NP + i];
    dist[j] = 1e10f;
  }
  __shared__ float sv[16];
  __shared__ int   si[16];
  __shared__ float sc[3];
  __shared__ int   snext;
  float* outX = out;                       // [B,3,S]
  float* outI = out + 24576 + 1048576;     // [B,S] as float

  if (t == 0) {
    sc[0] = px[0]; sc[1] = py[0]; sc[2] = pz[0];
    newXyz[(size_t)(b * SS) * 3 + 0] = px[0];
    newXyz[(size_t)(b * SS) * 3 + 1] = py[0];
    newXyz[(size_t)(b * SS) * 3 + 2] = pz[0];
    outX[(b * 3 + 0) * SS] = px[0];
    outX[(b * 3 + 1) * SS] = py[0];
    outX[(b * 3 + 2) * SS] = pz[0];
    outI[b * SS] = 0.0f;
  }
  __syncthreads();

  for (int it = 0; it < SS - 1; ++it) {
    float cx = sc[0], cy = sc[1], cz = sc[2];
    float best = -1.0f; int bi = 0;
#pragma unroll
    for (int j = 0; j < 8; j++) {
      float dx = __fsub_rn(px[j], cx);
      float dy = __fsub_rn(py[j], cy);
      float dz = __fsub_rn(pz[j], cz);
      float d = __fadd_rn(__fadd_rn(__fmul_rn(dx, dx), __fmul_rn(dy, dy)), __fmul_rn(dz, dz));
      float dm = fminf(dist[j], d);
      dist[j] = dm;
      if (dm > best) { best = dm; bi = t + (j << 10); } // ascending idx + strict > => lowest idx on tie
    }
    // wave argmax, lower-index tie-break
#pragma unroll
    for (int m = 1; m < 64; m <<= 1) {
      float ov = __shfl_xor(best, m, 64);
      int   oi = __shfl_xor(bi, m, 64);
      if (ov > best || (ov == best && oi < bi)) { best = ov; bi = oi; }
    }
    if ((t & 63) == 0) { sv[t >> 6] = best; si[t >> 6] = bi; }
    __syncthreads();
    if (t < 64) {
      float v  = (t < 16) ? sv[t] : -1.0f;
      int   ii = (t < 16) ? si[t] : 0x7fffffff;
#pragma unroll
      for (int m = 1; m < 64; m <<= 1) {
        float ov = __shfl_xor(v, m, 64);
        int   oi = __shfl_xor(ii, m, 64);
        if (ov > v || (ov == v && oi < ii)) { v = ov; ii = oi; }
      }
      if (t == 0) { snext = ii; outI[b * SS + it + 1] = (float)ii; }
    }
    __syncthreads();
    int nx = snext;
    if ((nx & 1023) == t) {
      int j = nx >> 10;
      sc[0] = px[j]; sc[1] = py[j]; sc[2] = pz[j];
      int s = it + 1;
      newXyz[(size_t)(b * SS + s) * 3 + 0] = px[j];
      newXyz[(size_t)(b * SS + s) * 3 + 1] = py[j];
      newXyz[(size_t)(b * SS + s) * 3 + 2] = pz[j];
      outX[(b * 3 + 0) * SS + s] = px[j];
      outX[(b * 3 + 1) * SS + s] = py[j];
      outX[(b * 3 + 2) * SS + s] = pz[j];
    }
    __syncthreads();
  }
}

// ---------------- kNN top-16: one wave per query ----------------
__global__ __launch_bounds__(256) void knn_kernel(
    const float* __restrict__ xyz, const float* __restrict__ newXyz,
    int* __restrict__ knnIdx)
{
  const int t = threadIdx.x, w = t >> 6, l = t & 63;
  const int q = blockIdx.x * 4 + w;
  const int b = q >> 11;
  const float* xb = xyz + (size_t)b * 3 * NP;
  float qx = newXyz[q * 3], qy = newXyz[q * 3 + 1], qz = newXyz[q * 3 + 2];
  float ss = __fadd_rn(__fadd_rn(__fmul_rn(qx, qx), __fmul_rn(qy, qy)), __fmul_rn(qz, qz));
  float kd[16]; int ki[16];
#pragma unroll
  for (int j = 0; j < 16; j++) { kd[j] = __builtin_inff(); ki[j] = 0x7fffffff; }

  for (int m = 0; m < 128; m++) {
    int i = l + (m << 6);
    float x = xb[i], y = xb[NP + i], z = xb[2 * NP + i];
    float dot = __fadd_rn(__fadd_rn(__fmul_rn(x, qx), __fmul_rn(y, qy)), __fmul_rn(z, qz));
    float nn  = __fadd_rn(__fadd_rn(__fmul_rn(x, x), __fmul_rn(y, y)), __fmul_rn(z, z));
    float d   = __fadd_rn(__fadd_rn(__fmul_rn(-2.0f, dot), ss), nn);
    if (d < kd[15]) {
      kd[15] = d; ki[15] = i;
#pragma unroll
      for (int jj = 15; jj >= 1; jj--) {
        if (kd[jj] < kd[jj - 1]) {
          float td = kd[jj]; kd[jj] = kd[jj - 1]; kd[jj - 1] = td;
          int   ti = ki[jj]; ki[jj] = ki[jj - 1]; ki[jj - 1] = ti;
        }
      }
    }
  }

  __shared__ float sd[4 * 64 * 17];
  __shared__ int   sx[4 * 64 * 17];
  int base = (w * 64 + l) * 17;
#pragma unroll
  for (int j = 0; j < 16; j++) { sd[base + j] = kd[j]; sx[base + j] = ki[j]; }
  __syncthreads();

  int cur = 0; int outIdx = 0;
#pragma unroll 1
  for (int r = 0; r < 16; r++) {
    float hv = (cur < 16) ? sd[base + cur] : __builtin_inff();
    int   hi = (cur < 16) ? sx[base + cur] : 0x7fffffff;
    int   hl = l;
#pragma unroll
    for (int m2 = 1; m2 < 64; m2 <<= 1) {
      float ov = __shfl_xor(hv, m2, 64);
      int   oi = __shfl_xor(hi, m2, 64);
      int   ol = __shfl_xor(hl, m2, 64);
      if (ov < hv || (ov == hv && oi < hi)) { hv = ov; hi = oi; hl = ol; }
    }
    if (l == hl) cur++;
    if (l == r) outIdx = hi;
  }
  if (l < 16) knnIdx[q * 16 + l] = outIdx;
}

// ---------------- gather + concat -> X0 [67][NN] ----------------
__global__ __launch_bounds__(256) void build_x0(
    const float* __restrict__ xyz, const float* __restrict__ points,
    const float* __restrict__ newXyz, const int* __restrict__ knnIdx,
    float* __restrict__ X)
{
  int n = blockIdx.x * 256 + threadIdx.x;
  int b = n >> 15;
  int q = n >> 4;
  int ip = knnIdx[n];
  const float* xb = xyz + (size_t)b * 3 * NP;
  X[(size_t)0 * NN + n] = xb[ip]          - newXyz[q * 3 + 0];
  X[(size_t)1 * NN + n] = xb[NP + ip]     - newXyz[q * 3 + 1];
  X[(size_t)2 * NN + n] = xb[2 * NP + ip] - newXyz[q * 3 + 2];
  const float* pb = points + (size_t)b * DD * NP;
#pragma unroll 8
  for (int d0 = 0; d0 < DD; d0++)
    X[(size_t)(3 + d0) * NN + n] = pb[(size_t)d0 * NP + ip];
}

// ---------------- 1x1 conv: Y[COUT][NN] = W[COUT][CIN] * X[CIN][NN] ----------------
template <int CIN, int COUT>
__global__ __launch_bounds__(256) void conv_kernel(
    const float* __restrict__ X, const float* __restrict__ W, float* __restrict__ Y)
{
  int n = blockIdx.x * 256 + threadIdx.x;
  float x[CIN];
#pragma unroll
  for (int c = 0; c < CIN; c++) x[c] = X[(size_t)c * NN + n];
#pragma unroll 1
  for (int o = 0; o < COUT; o += 4) {
    float a0 = 0.f, a1 = 0.f, a2 = 0.f, a3 = 0.f;
#pragma unroll
    for (int c = 0; c < CIN; c++) {
      float xv = x[c];
      a0 = fmaf(W[(o + 0) * CIN + c], xv, a0);
      a1 = fmaf(W[(o + 1) * CIN + c], xv, a1);
      a2 = fmaf(W[(o + 2) * CIN + c], xv, a2);
      a3 = fmaf(W[(o + 3) * CIN + c], xv, a3);
    }
    Y[(size_t)(o + 0) * NN + n] = a0;
    Y[(size_t)(o + 1) * NN + n] = a1;
    Y[(size_t)(o + 2) * NN + n] = a2;
    Y[(size_t)(o + 3) * NN + n] = a3;
  }
}

// ---------------- per-channel sum / sumsq ----------------
__global__ __launch_bounds__(256) void stats_kernel(
    const float* __restrict__ Y, float* __restrict__ stats)
{
  int c = blockIdx.y;
  int base = blockIdx.x * 4096 + threadIdx.x;
  const float* yc = Y + (size_t)c * NN;
  float s1 = 0.f, s2 = 0.f;
#pragma unroll
  for (int j = 0; j < 16; j++) {
    float v = yc[base + j * 256];
    s1 += v; s2 = fmaf(v, v, s2);
  }
#pragma unroll
  for (int m = 1; m < 64; m <<= 1) {
    s1 += __shfl_xor(s1, m, 64);
    s2 += __shfl_xor(s2, m, 64);
  }
  __shared__ float r1[4], r2[4];
  int w = threadIdx.x >> 6;
  if ((threadIdx.x & 63) == 0) { r1[w] = s1; r2[w] = s2; }
  __syncthreads();
  if (threadIdx.x == 0) {
    float t1 = r1[0] + r1[1] + r1[2] + r1[3];
    float t2 = r2[0] + r2[1] + r2[2] + r2[3];
    atomicAdd(&stats[c * 2], t1);
    atomicAdd(&stats[c * 2 + 1], t2);
  }
}

// ---------------- BN(train) + LeakyReLU, in place ----------------
__global__ __launch_bounds__(256) void bn_lrelu_kernel(
    float* __restrict__ Y, const float* __restrict__ stats,
    const float* __restrict__ g, const float* __restrict__ bt)
{
  int c = blockIdx.y;
  int n = blockIdx.x * 256 + threadIdx.x;
  float mean = stats[c * 2] * (1.0f / NN);
  float var  = stats[c * 2 + 1] * (1.0f / NN) - mean * mean;
  float inv  = rsqrtf(var + 1e-5f);
  float gamma = g[c], beta = bt[c];
  size_t o = (size_t)c * NN + n;
  float v = (Y[o] - mean) * inv;
  v = v * gamma + beta;
  Y[o] = v > 0.0f ? v : 0.1f * v;
}

// ---------------- max over K=16 -> feat [B,128,S] ----------------
__global__ __launch_bounds__(256) void maxk_kernel(
    const float* __restrict__ X, float* __restrict__ out)
{
  int m = blockIdx.x * 256 + threadIdx.x;
  int s = m & 2047;
  int o = (m >> 11) & 127;
  int b = m >> 18;
  const float4* p = (const float4*)(X + (size_t)o * NN + ((size_t)((b << 11) + s) << 4));
  float4 v0 = p[0], v1 = p[1], v2 = p[2], v3 = p[3];
  float mx = fmaxf(fmaxf(fmaxf(v0.x, v0.y), fmaxf(v0.z, v0.w)),
                   fmaxf(fmaxf(v1.x, v1.y), fmaxf(v1.z, v1.w)));
  mx = fmaxf(mx, fmaxf(fmaxf(fmaxf(v2.x, v2.y), fmaxf(v2.z, v2.w)),
                       fmaxf(fmaxf(v3.x, v3.y), fmaxf(v3.z, v3.w))));
  out[24576 + (size_t)((b << 7) + o) * SS + s] = mx;
}

extern "C" void kernel_launch(void* const* d_in, const int* in_sizes, int n_in,
                              void* d_out, int out_size, void* d_ws, size_t ws_size,
                              hipStream_t stream) {
  const float* xyz    = (const float*)d_in[0];
  const float* points = (const float*)d_in[1];
  const float* w0 = (const float*)d_in[2];
  const float* w1 = (const float*)d_in[3];
  const float* w2 = (const float*)d_in[4];
  const float* g0 = (const float*)d_in[5];
  const float* b0 = (const float*)d_in[6];
  const float* g1 = (const float*)d_in[7];
  const float* b1 = (const float*)d_in[8];
  const float* g2 = (const float*)d_in[9];
  const float* b2 = (const float*)d_in[10];
  float* out = (float*)d_out;

  float* wsf    = (float*)d_ws;
  float* newXyz = wsf;                       // 24576 floats  [q*3+c]
  int*   knnIdx = (int*)(wsf + 24576);       // 131072 ints
  float* stats  = wsf + 155648;              // 256 floats
  float* Xa     = wsf + 155904;              // 67*131072
  float* Xb     = wsf + 8937728;             // 128*131072

  fps_kernel<<<BB, 1024, 0, stream>>>(xyz, newXyz, out);
  knn_kernel<<<SS * BB / 4, 256, 0, stream>>>(xyz, newXyz, knnIdx);
  build_x0<<<NN / 256, 256, 0, stream>>>(xyz, points, newXyz, knnIdx, Xa);

  hipMemsetAsync(stats, 0, 256 * 4, stream);
  conv_kernel<67, 64><<<NN / 256, 256, 0, stream>>>(Xa, w0, Xb);
  stats_kernel<<<dim3(32, 64), 256, 0, stream>>>(Xb, stats);
  bn_lrelu_kernel<<<dim3(NN / 256, 64), 256, 0, stream>>>(Xb, stats, g0, b0);

  hipMemsetAsync(stats, 0, 256 * 4, stream);
  conv_kernel<64, 64><<<NN / 256, 256, 0, stream>>>(Xb, w1, Xa);
  stats_kernel<<<dim3(32, 64), 256, 0, stream>>>(Xa, stats);
  bn_lrelu_kernel<<<dim3(NN / 256, 64), 256, 0, stream>>>(Xa, stats, g1, b1);

  hipMemsetAsync(stats, 0, 256 * 4, stream);
  conv_kernel<64, 128><<<NN / 256, 256, 0, stream>>>(Xa, w2, Xb);
  stats_kernel<<<dim3(32, 128), 256, 0, stream>>>(Xb, stats);
  bn_lrelu_kernel<<<dim3(NN / 256, 128), 256, 0, stream>>>(Xb, stats, g2, b2);

  maxk_kernel<<<(BB * 128 * SS) / 256, 256, 0, stream>>>(Xb, out);
}

// Round 2
// 4088.478 us; speedup vs baseline: 1.1360x; 1.1360x over previous
//
#include <hip/hip_runtime.h>
#include <hip/hip_bf16.h>

#define BB 4
#define NP 8192
#define SS 2048
#define KK 16
#define DD 64
#define NN (BB*SS*KK) // 131072

// ---------------- FPS: one block per batch, bit-exact vs numpy ----------------
// No global memory ops inside the sequential loop; 2 barriers/iter; winner
// coords/index staged in LDS and flushed in parallel at the end.
__global__ __launch_bounds__(1024) void fps_kernel(
    const float* __restrict__ xyz, float* __restrict__ newXyz,
    float* __restrict__ out)
{
  const int b = blockIdx.x;
  const int t = threadIdx.x;
  const int wv = t >> 6, l = t & 63;
  const float* xb = xyz + (size_t)b * 3 * NP;

  __shared__ float sv[16];
  __shared__ int   si[16];
  __shared__ float sc[3];
  __shared__ float wxs[SS], wys[SS], wzs[SS];
  __shared__ int   wis[SS];

  float px[8], py[8], pz[8], dist[8];
#pragma unroll
  for (int j = 0; j < 8; j++) {
    int i = t + (j << 10);
    px[j] = xb[i]; py[j] = xb[NP + i]; pz[j] = xb[2 * NP + i];
    dist[j] = 1e10f;
  }
  if (t == 0) {
    sc[0] = px[0]; sc[1] = py[0]; sc[2] = pz[0];
    wxs[0] = px[0]; wys[0] = py[0]; wzs[0] = pz[0]; wis[0] = 0;
  }
  __syncthreads();

  for (int it = 1; it < SS; ++it) {
    float cx = sc[0], cy = sc[1], cz = sc[2];
    float best = -1.0f; int bi = 0;
#pragma unroll
    for (int j = 0; j < 8; j++) {
      float dx = __fsub_rn(px[j], cx);
      float dy = __fsub_rn(py[j], cy);
      float dz = __fsub_rn(pz[j], cz);
      float d = __fadd_rn(__fadd_rn(__fmul_rn(dx, dx), __fmul_rn(dy, dy)), __fmul_rn(dz, dz));
      float dm = fminf(dist[j], d);
      dist[j] = dm;
      if (dm > best) { best = dm; bi = t + (j << 10); } // ascending idx + strict > => lowest idx on tie
    }
    // wave argmax, lower-index tie-break
#pragma unroll
    for (int m = 1; m < 64; m <<= 1) {
      float ov = __shfl_xor(best, m, 64);
      int   oi = __shfl_xor(bi, m, 64);
      if (ov > best || (ov == best && oi < bi)) { best = ov; bi = oi; }
    }
    if (l == 0) { sv[wv] = best; si[wv] = bi; }
    __syncthreads();
    // every wave redundantly reduces the 16 wave-winners -> all threads know winner
    float v  = sv[l & 15];
    int   ii = si[l & 15];
#pragma unroll
    for (int m = 1; m < 16; m <<= 1) {
      float ov = __shfl_xor(v, m, 64);
      int   oi = __shfl_xor(ii, m, 64);
      if (ov > v || (ov == v && oi < ii)) { v = ov; ii = oi; }
    }
    // owner thread publishes winner coords to LDS (registers -> LDS only)
    if (t == (ii & 1023)) {
      int jw = ii >> 10;
      float sx_ = px[0], sy_ = py[0], sz_ = pz[0];
#pragma unroll
      for (int j2 = 1; j2 < 8; j2++) {
        if (jw == j2) { sx_ = px[j2]; sy_ = py[j2]; sz_ = pz[j2]; }
      }
      sc[0] = sx_; sc[1] = sy_; sc[2] = sz_;
      wxs[it] = sx_; wys[it] = sy_; wzs[it] = sz_; wis[it] = ii;
    }
    __syncthreads();
  }

  // parallel flush of all outputs
  float* outX = out;                       // [B,3,S]
  float* outI = out + 24576 + 1048576;     // [B,S] as float
  for (int s = t; s < SS; s += 1024) {
    float x = wxs[s], y = wys[s], z = wzs[s];
    size_t q = (size_t)(b * SS + s);
    newXyz[q * 3 + 0] = x;
    newXyz[q * 3 + 1] = y;
    newXyz[q * 3 + 2] = z;
    outX[(b * 3 + 0) * SS + s] = x;
    outX[(b * 3 + 1) * SS + s] = y;
    outX[(b * 3 + 2) * SS + s] = z;
    outI[b * SS + s] = (float)wis[s];
  }
}

// ---------------- kNN top-16: one wave per query ----------------
__global__ __launch_bounds__(256) void knn_kernel(
    const float* __restrict__ xyz, const float* __restrict__ newXyz,
    int* __restrict__ knnIdx)
{
  const int t = threadIdx.x, w = t >> 6, l = t & 63;
  const int q = blockIdx.x * 4 + w;
  const int b = q >> 11;
  const float* xb = xyz + (size_t)b * 3 * NP;
  float qx = newXyz[q * 3], qy = newXyz[q * 3 + 1], qz = newXyz[q * 3 + 2];
  float ss = __fadd_rn(__fadd_rn(__fmul_rn(qx, qx), __fmul_rn(qy, qy)), __fmul_rn(qz, qz));
  float kd[16]; int ki[16];
#pragma unroll
  for (int j = 0; j < 16; j++) { kd[j] = __builtin_inff(); ki[j] = 0x7fffffff; }

  for (int m = 0; m < 128; m++) {
    int i = l + (m << 6);
    float x = xb[i], y = xb[NP + i], z = xb[2 * NP + i];
    float dot = __fadd_rn(__fadd_rn(__fmul_rn(x, qx), __fmul_rn(y, qy)), __fmul_rn(z, qz));
    float nn  = __fadd_rn(__fadd_rn(__fmul_rn(x, x), __fmul_rn(y, y)), __fmul_rn(z, z));
    float d   = __fadd_rn(__fadd_rn(__fmul_rn(-2.0f, dot), ss), nn);
    if (d < kd[15]) {
      kd[15] = d; ki[15] = i;
#pragma unroll
      for (int jj = 15; jj >= 1; jj--) {
        if (kd[jj] < kd[jj - 1]) {
          float td = kd[jj]; kd[jj] = kd[jj - 1]; kd[jj - 1] = td;
          int   ti = ki[jj]; ki[jj] = ki[jj - 1]; ki[jj - 1] = ti;
        }
      }
    }
  }

  __shared__ float sd[4 * 64 * 17];
  __shared__ int   sx[4 * 64 * 17];
  int base = (w * 64 + l) * 17;
#pragma unroll
  for (int j = 0; j < 16; j++) { sd[base + j] = kd[j]; sx[base + j] = ki[j]; }
  __syncthreads();

  int cur = 0; int outIdx = 0;
#pragma unroll 1
  for (int r = 0; r < 16; r++) {
    float hv = (cur < 16) ? sd[base + cur] : __builtin_inff();
    int   hi = (cur < 16) ? sx[base + cur] : 0x7fffffff;
    int   hl = l;
#pragma unroll
    for (int m2 = 1; m2 < 64; m2 <<= 1) {
      float ov = __shfl_xor(hv, m2, 64);
      int   oi = __shfl_xor(hi, m2, 64);
      int   ol = __shfl_xor(hl, m2, 64);
      if (ov < hv || (ov == hv && oi < hi)) { hv = ov; hi = oi; hl = ol; }
    }
    if (l == hl) cur++;
    if (l == r) outIdx = hi;
  }
  if (l < 16) knnIdx[q * 16 + l] = outIdx;
}

// ---------------- gather + concat -> X0 [67][NN] ----------------
__global__ __launch_bounds__(256) void build_x0(
    const float* __restrict__ xyz, const float* __restrict__ points,
    const float* __restrict__ newXyz, const int* __restrict__ knnIdx,
    float* __restrict__ X)
{
  int n = blockIdx.x * 256 + threadIdx.x;
  int b = n >> 15;
  int q = n >> 4;
  int ip = knnIdx[n];
  const float* xb = xyz + (size_t)b * 3 * NP;
  X[(size_t)0 * NN + n] = xb[ip]          - newXyz[q * 3 + 0];
  X[(size_t)1 * NN + n] = xb[NP + ip]     - newXyz[q * 3 + 1];
  X[(size_t)2 * NN + n] = xb[2 * NP + ip] - newXyz[q * 3 + 2];
  const float* pb = points + (size_t)b * DD * NP;
#pragma unroll 8
  for (int d0 = 0; d0 < DD; d0++)
    X[(size_t)(3 + d0) * NN + n] = pb[(size_t)d0 * NP + ip];
}

// ---------------- 1x1 conv: Y[COUT][NN] = W[COUT][CIN] * X[CIN][NN] ----------------
template <int CIN, int COUT>
__global__ __launch_bounds__(256) void conv_kernel(
    const float* __restrict__ X, const float* __restrict__ W, float* __restrict__ Y)
{
  int n = blockIdx.x * 256 + threadIdx.x;
  float x[CIN];
#pragma unroll
  for (int c = 0; c < CIN; c++) x[c] = X[(size_t)c * NN + n];
#pragma unroll 1
  for (int o = 0; o < COUT; o += 4) {
    float a0 = 0.f, a1 = 0.f, a2 = 0.f, a3 = 0.f;
#pragma unroll
    for (int c = 0; c < CIN; c++) {
      float xv = x[c];
      a0 = fmaf(W[(o + 0) * CIN + c], xv, a0);
      a1 = fmaf(W[(o + 1) * CIN + c], xv, a1);
      a2 = fmaf(W[(o + 2) * CIN + c], xv, a2);
      a3 = fmaf(W[(o + 3) * CIN + c], xv, a3);
    }
    Y[(size_t)(o + 0) * NN + n] = a0;
    Y[(size_t)(o + 1) * NN + n] = a1;
    Y[(size_t)(o + 2) * NN + n] = a2;
    Y[(size_t)(o + 3) * NN + n] = a3;
  }
}

// ---------------- per-channel sum / sumsq ----------------
__global__ __launch_bounds__(256) void stats_kernel(
    const float* __restrict__ Y, float* __restrict__ stats)
{
  int c = blockIdx.y;
  int base = blockIdx.x * 4096 + threadIdx.x;
  const float* yc = Y + (size_t)c * NN;
  float s1 = 0.f, s2 = 0.f;
#pragma unroll
  for (int j = 0; j < 16; j++) {
    float v = yc[base + j * 256];
    s1 += v; s2 = fmaf(v, v, s2);
  }
#pragma unroll
  for (int m = 1; m < 64; m <<= 1) {
    s1 += __shfl_xor(s1, m, 64);
    s2 += __shfl_xor(s2, m, 64);
  }
  __shared__ float r1[4], r2[4];
  int w = threadIdx.x >> 6;
  if ((threadIdx.x & 63) == 0) { r1[w] = s1; r2[w] = s2; }
  __syncthreads();
  if (threadIdx.x == 0) {
    float t1 = r1[0] + r1[1] + r1[2] + r1[3];
    float t2 = r2[0] + r2[1] + r2[2] + r2[3];
    atomicAdd(&stats[c * 2], t1);
    atomicAdd(&stats[c * 2 + 1], t2);
  }
}

// ---------------- BN(train) + LeakyReLU, in place ----------------
__global__ __launch_bounds__(256) void bn_lrelu_kernel(
    float* __restrict__ Y, const float* __restrict__ stats,
    const float* __restrict__ g, const float* __restrict__ bt)
{
  int c = blockIdx.y;
  int n = blockIdx.x * 256 + threadIdx.x;
  float mean = stats[c * 2] * (1.0f / NN);
  float var  = stats[c * 2 + 1] * (1.0f / NN) - mean * mean;
  float inv  = rsqrtf(var + 1e-5f);
  float gamma = g[c], beta = bt[c];
  size_t o = (size_t)c * NN + n;
  float v = (Y[o] - mean) * inv;
  v = v * gamma + beta;
  Y[o] = v > 0.0f ? v : 0.1f * v;
}

// ---------------- max over K=16 -> feat [B,128,S] ----------------
__global__ __launch_bounds__(256) void maxk_kernel(
    const float* __restrict__ X, float* __restrict__ out)
{
  int m = blockIdx.x * 256 + threadIdx.x;
  int s = m & 2047;
  int o = (m >> 11) & 127;
  int b = m >> 18;
  const float4* p = (const float4*)(X + (size_t)o * NN + ((size_t)((b << 11) + s) << 4));
  float4 v0 = p[0], v1 = p[1], v2 = p[2], v3 = p[3];
  float mx = fmaxf(fmaxf(fmaxf(v0.x, v0.y), fmaxf(v0.z, v0.w)),
                   fmaxf(fmaxf(v1.x, v1.y), fmaxf(v1.z, v1.w)));
  mx = fmaxf(mx, fmaxf(fmaxf(fmaxf(v2.x, v2.y), fmaxf(v2.z, v2.w)),
                       fmaxf(fmaxf(v3.x, v3.y), fmaxf(v3.z, v3.w))));
  out[24576 + (size_t)((b << 7) + o) * SS + s] = mx;
}

extern "C" void kernel_launch(void* const* d_in, const int* in_sizes, int n_in,
                              void* d_out, int out_size, void* d_ws, size_t ws_size,
                              hipStream_t stream) {
  const float* xyz    = (const float*)d_in[0];
  const float* points = (const float*)d_in[1];
  const float* w0 = (const float*)d_in[2];
  const float* w1 = (const float*)d_in[3];
  const float* w2 = (const float*)d_in[4];
  const float* g0 = (const float*)d_in[5];
  const float* b0 = (const float*)d_in[6];
  const float* g1 = (const float*)d_in[7];
  const float* b1 = (const float*)d_in[8];
  const float* g2 = (const float*)d_in[9];
  const float* b2 = (const float*)d_in[10];
  float* out = (float*)d_out;

  float* wsf    = (float*)d_ws;
  float* newXyz = wsf;                       // 24576 floats  [q*3+c]
  int*   knnIdx = (int*)(wsf + 24576);       // 131072 ints
  float* stats  = wsf + 155648;              // 256 floats
  float* Xa     = wsf + 155904;              // 67*131072
  float* Xb     = wsf + 8937728;             // 128*131072

  fps_kernel<<<BB, 1024, 0, stream>>>(xyz, newXyz, out);
  knn_kernel<<<SS * BB / 4, 256, 0, stream>>>(xyz, newXyz, knnIdx);
  build_x0<<<NN / 256, 256, 0, stream>>>(xyz, points, newXyz, knnIdx, Xa);

  hipMemsetAsync(stats, 0, 256 * 4, stream);
  conv_kernel<67, 64><<<NN / 256, 256, 0, stream>>>(Xa, w0, Xb);
  stats_kernel<<<dim3(32, 64), 256, 0, stream>>>(Xb, stats);
  bn_lrelu_kernel<<<dim3(NN / 256, 64), 256, 0, stream>>>(Xb, stats, g0, b0);

  hipMemsetAsync(stats, 0, 256 * 4, stream);
  conv_kernel<64, 64><<<NN / 256, 256, 0, stream>>>(Xb, w1, Xa);
  stats_kernel<<<dim3(32, 64), 256, 0, stream>>>(Xa, stats);
  bn_lrelu_kernel<<<dim3(NN / 256, 64), 256, 0, stream>>>(Xa, stats, g1, b1);

  hipMemsetAsync(stats, 0, 256 * 4, stream);
  conv_kernel<64, 128><<<NN / 256, 256, 0, stream>>>(Xa, w2, Xb);
  stats_kernel<<<dim3(32, 128), 256, 0, stream>>>(Xb, stats);
  bn_lrelu_kernel<<<dim3(NN / 256, 128), 256, 0, stream>>>(Xb, stats, g2, b2);

  maxk_kernel<<<(BB * 128 * SS) / 256, 256, 0, stream>>>(Xb, out);
}

// Round 3
// 2768.847 us; speedup vs baseline: 1.6774x; 1.4766x over previous
//
#include <hip/hip_runtime.h>
#include <hip/hip_bf16.h>

#define BB 4
#define NP 8192
#define SS 2048
#define KK 16
#define DD 64
#define NN (BB*SS*KK) // 131072

// ---------------- FPS: one block per batch, bit-exact vs numpy ----------------
// All coords in LDS so every thread can fetch the winner's centroid by index:
// ONE barrier per iteration, u64-packed argmax (value<<32 | ~idx) for a
// single-max reduce with lowest-index tie-break. Winner array double-buffered
// by parity (skew < 1 iter with one barrier).
__global__ __launch_bounds__(512) void fps_kernel(
    const float* __restrict__ xyz, float* __restrict__ newXyz,
    float* __restrict__ out)
{
  const int b = blockIdx.x;
  const int t = threadIdx.x;
  const int wv = t >> 6, l = t & 63;
  const float* xb = xyz + (size_t)b * 3 * NP;

  __shared__ float lx[NP], ly[NP], lz[NP];
  __shared__ int   wis[SS];
  __shared__ unsigned long long swin[2][8];

  float px[16], py[16], pz[16], dist[16];
#pragma unroll
  for (int j = 0; j < 16; j++) {
    int i = t + (j << 9);
    float x = xb[i], y = xb[NP + i], z = xb[2 * NP + i];
    px[j] = x; py[j] = y; pz[j] = z; dist[j] = 1e10f;
    lx[i] = x; ly[i] = y; lz[i] = z;
  }
  if (t == 0) wis[0] = 0;
  __syncthreads();

  int ii = 0;
  for (int it = 1; it < SS; ++it) {
    // broadcast read of current centroid (all lanes same address)
    float cx = lx[ii], cy = ly[ii], cz = lz[ii];
    float best = -1.0f; int bi = 0;
#pragma unroll
    for (int j = 0; j < 16; j++) {
      float dx = __fsub_rn(px[j], cx);
      float dy = __fsub_rn(py[j], cy);
      float dz = __fsub_rn(pz[j], cz);
      float d = __fadd_rn(__fadd_rn(__fmul_rn(dx, dx), __fmul_rn(dy, dy)), __fmul_rn(dz, dz));
      float dm = fminf(dist[j], d);
      dist[j] = dm;
      if (dm > best) { best = dm; bi = t + (j << 9); } // ascending idx + strict > => lowest idx on tie
    }
    // pack: non-negative float bits are monotonic; ~idx makes ties pick lowest idx
    unsigned long long pk =
        ((unsigned long long)__float_as_uint(best) << 32) | (unsigned)(~bi);
#pragma unroll
    for (int m = 1; m < 64; m <<= 1) {
      unsigned long long o = __shfl_xor(pk, m, 64);
      pk = (o > pk) ? o : pk;
    }
    int p = it & 1;
    if (l == 0) swin[p][wv] = pk;
    __syncthreads();
    unsigned long long v = swin[p][l & 7];
#pragma unroll
    for (int m = 1; m < 8; m <<= 1) {
      unsigned long long o = __shfl_xor(v, m, 64);
      v = (o > v) ? o : v;
    }
    ii = (int)(~((unsigned)v));
    if (t == 0) wis[it] = ii;
  }
  __syncthreads();

  // parallel flush of all outputs
  float* outX = out;                       // [B,3,S]
  float* outI = out + 24576 + 1048576;     // [B,S] as float
  for (int s = t; s < SS; s += 512) {
    int iw = wis[s];
    float x = lx[iw], y = ly[iw], z = lz[iw];
    size_t q = (size_t)(b * SS + s);
    newXyz[q * 3 + 0] = x;
    newXyz[q * 3 + 1] = y;
    newXyz[q * 3 + 2] = z;
    outX[(b * 3 + 0) * SS + s] = x;
    outX[(b * 3 + 1) * SS + s] = y;
    outX[(b * 3 + 2) * SS + s] = z;
    outI[b * SS + s] = (float)iw;
  }
}

// ---------------- kNN top-16: one wave per query ----------------
__global__ __launch_bounds__(256) void knn_kernel(
    const float* __restrict__ xyz, const float* __restrict__ newXyz,
    int* __restrict__ knnIdx)
{
  const int t = threadIdx.x, w = t >> 6, l = t & 63;
  const int q = blockIdx.x * 4 + w;
  const int b = q >> 11;
  const float* xb = xyz + (size_t)b * 3 * NP;
  float qx = newXyz[q * 3], qy = newXyz[q * 3 + 1], qz = newXyz[q * 3 + 2];
  float ss = __fadd_rn(__fadd_rn(__fmul_rn(qx, qx), __fmul_rn(qy, qy)), __fmul_rn(qz, qz));
  float kd[16]; int ki[16];
#pragma unroll
  for (int j = 0; j < 16; j++) { kd[j] = __builtin_inff(); ki[j] = 0x7fffffff; }

  for (int m = 0; m < 128; m++) {
    int i = l + (m << 6);
    float x = xb[i], y = xb[NP + i], z = xb[2 * NP + i];
    float dot = __fadd_rn(__fadd_rn(__fmul_rn(x, qx), __fmul_rn(y, qy)), __fmul_rn(z, qz));
    float nn  = __fadd_rn(__fadd_rn(__fmul_rn(x, x), __fmul_rn(y, y)), __fmul_rn(z, z));
    float d   = __fadd_rn(__fadd_rn(__fmul_rn(-2.0f, dot), ss), nn);
    if (d < kd[15]) {
      kd[15] = d; ki[15] = i;
#pragma unroll
      for (int jj = 15; jj >= 1; jj--) {
        if (kd[jj] < kd[jj - 1]) {
          float td = kd[jj]; kd[jj] = kd[jj - 1]; kd[jj - 1] = td;
          int   ti = ki[jj]; ki[jj] = ki[jj - 1]; ki[jj - 1] = ti;
        }
      }
    }
  }

  __shared__ float sd[4 * 64 * 17];
  __shared__ int   sx[4 * 64 * 17];
  int base = (w * 64 + l) * 17;
#pragma unroll
  for (int j = 0; j < 16; j++) { sd[base + j] = kd[j]; sx[base + j] = ki[j]; }
  __syncthreads();

  int cur = 0; int outIdx = 0;
#pragma unroll 1
  for (int r = 0; r < 16; r++) {
    float hv = (cur < 16) ? sd[base + cur] : __builtin_inff();
    int   hi = (cur < 16) ? sx[base + cur] : 0x7fffffff;
    int   hl = l;
#pragma unroll
    for (int m2 = 1; m2 < 64; m2 <<= 1) {
      float ov = __shfl_xor(hv, m2, 64);
      int   oi = __shfl_xor(hi, m2, 64);
      int   ol = __shfl_xor(hl, m2, 64);
      if (ov < hv || (ov == hv && oi < hi)) { hv = ov; hi = oi; hl = ol; }
    }
    if (l == hl) cur++;
    if (l == r) outIdx = hi;
  }
  if (l < 16) knnIdx[q * 16 + l] = outIdx;
}

// ---------------- gather + concat -> X0 [67][NN] ----------------
__global__ __launch_bounds__(256) void build_x0(
    const float* __restrict__ xyz, const float* __restrict__ points,
    const float* __restrict__ newXyz, const int* __restrict__ knnIdx,
    float* __restrict__ X)
{
  int n = blockIdx.x * 256 + threadIdx.x;
  int b = n >> 15;
  int q = n >> 4;
  int ip = knnIdx[n];
  const float* xb = xyz + (size_t)b * 3 * NP;
  X[(size_t)0 * NN + n] = xb[ip]          - newXyz[q * 3 + 0];
  X[(size_t)1 * NN + n] = xb[NP + ip]     - newXyz[q * 3 + 1];
  X[(size_t)2 * NN + n] = xb[2 * NP + ip] - newXyz[q * 3 + 2];
  const float* pb = points + (size_t)b * DD * NP;
#pragma unroll 8
  for (int d0 = 0; d0 < DD; d0++)
    X[(size_t)(3 + d0) * NN + n] = pb[(size_t)d0 * NP + ip];
}

// ---------------- 1x1 conv: Y[COUT][NN] = W[COUT][CIN] * X[CIN][NN] ----------------
template <int CIN, int COUT>
__global__ __launch_bounds__(256) void conv_kernel(
    const float* __restrict__ X, const float* __restrict__ W, float* __restrict__ Y)
{
  int n = blockIdx.x * 256 + threadIdx.x;
  float x[CIN];
#pragma unroll
  for (int c = 0; c < CIN; c++) x[c] = X[(size_t)c * NN + n];
#pragma unroll 1
  for (int o = 0; o < COUT; o += 4) {
    float a0 = 0.f, a1 = 0.f, a2 = 0.f, a3 = 0.f;
#pragma unroll
    for (int c = 0; c < CIN; c++) {
      float xv = x[c];
      a0 = fmaf(W[(o + 0) * CIN + c], xv, a0);
      a1 = fmaf(W[(o + 1) * CIN + c], xv, a1);
      a2 = fmaf(W[(o + 2) * CIN + c], xv, a2);
      a3 = fmaf(W[(o + 3) * CIN + c], xv, a3);
    }
    Y[(size_t)(o + 0) * NN + n] = a0;
    Y[(size_t)(o + 1) * NN + n] = a1;
    Y[(size_t)(o + 2) * NN + n] = a2;
    Y[(size_t)(o + 3) * NN + n] = a3;
  }
}

// ---------------- per-channel sum / sumsq ----------------
__global__ __launch_bounds__(256) void stats_kernel(
    const float* __restrict__ Y, float* __restrict__ stats)
{
  int c = blockIdx.y;
  int base = blockIdx.x * 4096 + threadIdx.x;
  const float* yc = Y + (size_t)c * NN;
  float s1 = 0.f, s2 = 0.f;
#pragma unroll
  for (int j = 0; j < 16; j++) {
    float v = yc[base + j * 256];
    s1 += v; s2 = fmaf(v, v, s2);
  }
#pragma unroll
  for (int m = 1; m < 64; m <<= 1) {
    s1 += __shfl_xor(s1, m, 64);
    s2 += __shfl_xor(s2, m, 64);
  }
  __shared__ float r1[4], r2[4];
  int w = threadIdx.x >> 6;
  if ((threadIdx.x & 63) == 0) { r1[w] = s1; r2[w] = s2; }
  __syncthreads();
  if (threadIdx.x == 0) {
    float t1 = r1[0] + r1[1] + r1[2] + r1[3];
    float t2 = r2[0] + r2[1] + r2[2] + r2[3];
    atomicAdd(&stats[c * 2], t1);
    atomicAdd(&stats[c * 2 + 1], t2);
  }
}

// ---------------- BN(train) + LeakyReLU, in place ----------------
__global__ __launch_bounds__(256) void bn_lrelu_kernel(
    float* __restrict__ Y, const float* __restrict__ stats,
    const float* __restrict__ g, const float* __restrict__ bt)
{
  int c = blockIdx.y;
  int n = blockIdx.x * 256 + threadIdx.x;
  float mean = stats[c * 2] * (1.0f / NN);
  float var  = stats[c * 2 + 1] * (1.0f / NN) - mean * mean;
  float inv  = rsqrtf(var + 1e-5f);
  float gamma = g[c], beta = bt[c];
  size_t o = (size_t)c * NN + n;
  float v = (Y[o] - mean) * inv;
  v = v * gamma + beta;
  Y[o] = v > 0.0f ? v : 0.1f * v;
}

// ---------------- max over K=16 -> feat [B,128,S] ----------------
__global__ __launch_bounds__(256) void maxk_kernel(
    const float* __restrict__ X, float* __restrict__ out)
{
  int m = blockIdx.x * 256 + threadIdx.x;
  int s = m & 2047;
  int o = (m >> 11) & 127;
  int b = m >> 18;
  const float4* p = (const float4*)(X + (size_t)o * NN + ((size_t)((b << 11) + s) << 4));
  float4 v0 = p[0], v1 = p[1], v2 = p[2], v3 = p[3];
  float mx = fmaxf(fmaxf(fmaxf(v0.x, v0.y), fmaxf(v0.z, v0.w)),
                   fmaxf(fmaxf(v1.x, v1.y), fmaxf(v1.z, v1.w)));
  mx = fmaxf(mx, fmaxf(fmaxf(fmaxf(v2.x, v2.y), fmaxf(v2.z, v2.w)),
                       fmaxf(fmaxf(v3.x, v3.y), fmaxf(v3.z, v3.w))));
  out[24576 + (size_t)((b << 7) + o) * SS + s] = mx;
}

extern "C" void kernel_launch(void* const* d_in, const int* in_sizes, int n_in,
                              void* d_out, int out_size, void* d_ws, size_t ws_size,
                              hipStream_t stream) {
  const float* xyz    = (const float*)d_in[0];
  const float* points = (const float*)d_in[1];
  const float* w0 = (const float*)d_in[2];
  const float* w1 = (const float*)d_in[3];
  const float* w2 = (const float*)d_in[4];
  const float* g0 = (const float*)d_in[5];
  const float* b0 = (const float*)d_in[6];
  const float* g1 = (const float*)d_in[7];
  const float* b1 = (const float*)d_in[8];
  const float* g2 = (const float*)d_in[9];
  const float* b2 = (const float*)d_in[10];
  float* out = (float*)d_out;

  float* wsf    = (float*)d_ws;
  float* newXyz = wsf;                       // 24576 floats  [q*3+c]
  int*   knnIdx = (int*)(wsf + 24576);       // 131072 ints
  float* stats  = wsf + 155648;              // 256 floats
  float* Xa     = wsf + 155904;              // 67*131072
  float* Xb     = wsf + 8937728;             // 128*131072

  fps_kernel<<<BB, 512, 0, stream>>>(xyz, newXyz, out);
  knn_kernel<<<SS * BB / 4, 256, 0, stream>>>(xyz, newXyz, knnIdx);
  build_x0<<<NN / 256, 256, 0, stream>>>(xyz, points, newXyz, knnIdx, Xa);

  hipMemsetAsync(stats, 0, 256 * 4, stream);
  conv_kernel<67, 64><<<NN / 256, 256, 0, stream>>>(Xa, w0, Xb);
  stats_kernel<<<dim3(32, 64), 256, 0, stream>>>(Xb, stats);
  bn_lrelu_kernel<<<dim3(NN / 256, 64), 256, 0, stream>>>(Xb, stats, g0, b0);

  hipMemsetAsync(stats, 0, 256 * 4, stream);
  conv_kernel<64, 64><<<NN / 256, 256, 0, stream>>>(Xb, w1, Xa);
  stats_kernel<<<dim3(32, 64), 256, 0, stream>>>(Xa, stats);
  bn_lrelu_kernel<<<dim3(NN / 256, 64), 256, 0, stream>>>(Xa, stats, g1, b1);

  hipMemsetAsync(stats, 0, 256 * 4, stream);
  conv_kernel<64, 128><<<NN / 256, 256, 0, stream>>>(Xa, w2, Xb);
  stats_kernel<<<dim3(32, 128), 256, 0, stream>>>(Xb, stats);
  bn_lrelu_kernel<<<dim3(NN / 256, 128), 256, 0, stream>>>(Xb, stats, g2, b2);

  maxk_kernel<<<(BB * 128 * SS) / 256, 256, 0, stream>>>(Xb, out);
}

// Round 4
// 2734.622 us; speedup vs baseline: 1.6984x; 1.0125x over previous
//
#include <hip/hip_runtime.h>
#include <hip/hip_bf16.h>

#define BB 4
#define NP 8192
#define SS 2048
#define KK 16
#define DD 64
#define NN (BB*SS*KK) // 131072

// wave64 all-lanes f32 max: 4 DPP steps (row-local) + xor16 swizzle + xor32
__device__ __forceinline__ float wave_max_f32(float v) {
  int x;
  x = __builtin_amdgcn_update_dpp(0, __float_as_int(v), 0xB1, 0xF, 0xF, true);  // quad_perm xor1
  v = fmaxf(v, __int_as_float(x));
  x = __builtin_amdgcn_update_dpp(0, __float_as_int(v), 0x4E, 0xF, 0xF, true);  // quad_perm xor2
  v = fmaxf(v, __int_as_float(x));
  x = __builtin_amdgcn_update_dpp(0, __float_as_int(v), 0x141, 0xF, 0xF, true); // row_half_mirror (xor4)
  v = fmaxf(v, __int_as_float(x));
  x = __builtin_amdgcn_update_dpp(0, __float_as_int(v), 0x140, 0xF, 0xF, true); // row_mirror (xor8)
  v = fmaxf(v, __int_as_float(x));
  x = __builtin_amdgcn_ds_swizzle(__float_as_int(v), 0x401F);                   // xor16
  v = fmaxf(v, __int_as_float(x));
  v = fmaxf(v, __shfl_xor(v, 32, 64));                                          // xor32
  return v;
}

// ---------------- FPS: one block per batch, bit-exact vs numpy ----------------
// Per iter: dist update + per-thread fmax only; wave max via DPP; matching
// threads rescan for their lowest idx and atomicMax a packed (val,~idx) u64
// into a 3-way-rotated LDS slot; one barrier; broadcast read -> winner.
__global__ __launch_bounds__(512) void fps_kernel(
    const float* __restrict__ xyz, float* __restrict__ newXyz,
    float* __restrict__ out)
{
  const int b = blockIdx.x;
  const int t = threadIdx.x;
  const float* xb = xyz + (size_t)b * 3 * NP;

  __shared__ float lx[NP], ly[NP], lz[NP];
  __shared__ int   wis[SS];
  __shared__ unsigned long long swin[3];

  float px[16], py[16], pz[16], dist[16];
#pragma unroll
  for (int j = 0; j < 16; j++) {
    int i = t + (j << 9);
    float x = xb[i], y = xb[NP + i], z = xb[2 * NP + i];
    px[j] = x; py[j] = y; pz[j] = z; dist[j] = 1e10f;
    lx[i] = x; ly[i] = y; lz[i] = z;
  }
  if (t == 0) { wis[0] = 0; swin[0] = 0; swin[1] = 0; swin[2] = 0; }
  __syncthreads();

  float cx = lx[0], cy = ly[0], cz = lz[0];

  for (int it = 1; it < SS; ++it) {
    float lbest = -1.0f;
#pragma unroll
    for (int j = 0; j < 16; j++) {
      float dx = __fsub_rn(px[j], cx);
      float dy = __fsub_rn(py[j], cy);
      float dz = __fsub_rn(pz[j], cz);
      float d = __fadd_rn(__fadd_rn(__fmul_rn(dx, dx), __fmul_rn(dy, dy)), __fmul_rn(dz, dz));
      float dm = fminf(dist[j], d);
      dist[j] = dm;
      lbest = fmaxf(lbest, dm);
    }
    float Vw = wave_max_f32(lbest);
    int q = it % 3;
    if (lbest == Vw) {
      // lowest index j with dist[j]==Vw (descending scan keeps smallest)
      unsigned mi = 0u;
#pragma unroll
      for (int j = 15; j >= 0; j--) {
        if (dist[j] == Vw) mi = (unsigned)(t + (j << 9));
      }
      unsigned long long pk =
          ((unsigned long long)__float_as_uint(Vw) << 32) | (unsigned)(~mi);
      atomicMax(&swin[q], pk);
    }
    __syncthreads();
    unsigned long long pkf = swin[q];
    int ii = (int)(~((unsigned)pkf));
    if (t == 0) { wis[it] = ii; swin[(q + 2) % 3] = 0; }
    cx = lx[ii]; cy = ly[ii]; cz = lz[ii];
  }
  __syncthreads();

  // parallel flush of all outputs
  float* outX = out;                       // [B,3,S]
  float* outI = out + 24576 + 1048576;     // [B,S] as float
  for (int s = t; s < SS; s += 512) {
    int iw = wis[s];
    float x = lx[iw], y = ly[iw], z = lz[iw];
    size_t qq = (size_t)(b * SS + s);
    newXyz[qq * 3 + 0] = x;
    newXyz[qq * 3 + 1] = y;
    newXyz[qq * 3 + 2] = z;
    outX[(b * 3 + 0) * SS + s] = x;
    outX[(b * 3 + 1) * SS + s] = y;
    outX[(b * 3 + 2) * SS + s] = z;
    outI[b * SS + s] = (float)iw;
  }
}

// ---------------- kNN top-16: one wave per query ----------------
__global__ __launch_bounds__(256) void knn_kernel(
    const float* __restrict__ xyz, const float* __restrict__ newXyz,
    int* __restrict__ knnIdx)
{
  const int t = threadIdx.x, w = t >> 6, l = t & 63;
  const int q = blockIdx.x * 4 + w;
  const int b = q >> 11;
  const float* xb = xyz + (size_t)b * 3 * NP;
  float qx = newXyz[q * 3], qy = newXyz[q * 3 + 1], qz = newXyz[q * 3 + 2];
  float ss = __fadd_rn(__fadd_rn(__fmul_rn(qx, qx), __fmul_rn(qy, qy)), __fmul_rn(qz, qz));
  float kd[16]; int ki[16];
#pragma unroll
  for (int j = 0; j < 16; j++) { kd[j] = __builtin_inff(); ki[j] = 0x7fffffff; }

  for (int m = 0; m < 128; m++) {
    int i = l + (m << 6);
    float x = xb[i], y = xb[NP + i], z = xb[2 * NP + i];
    float dot = __fadd_rn(__fadd_rn(__fmul_rn(x, qx), __fmul_rn(y, qy)), __fmul_rn(z, qz));
    float nn  = __fadd_rn(__fadd_rn(__fmul_rn(x, x), __fmul_rn(y, y)), __fmul_rn(z, z));
    float d   = __fadd_rn(__fadd_rn(__fmul_rn(-2.0f, dot), ss), nn);
    if (d < kd[15]) {
      kd[15] = d; ki[15] = i;
#pragma unroll
      for (int jj = 15; jj >= 1; jj--) {
        if (kd[jj] < kd[jj - 1]) {
          float td = kd[jj]; kd[jj] = kd[jj - 1]; kd[jj - 1] = td;
          int   ti = ki[jj]; ki[jj] = ki[jj - 1]; ki[jj - 1] = ti;
        }
      }
    }
  }

  __shared__ float sd[4 * 64 * 17];
  __shared__ int   sx[4 * 64 * 17];
  int base = (w * 64 + l) * 17;
#pragma unroll
  for (int j = 0; j < 16; j++) { sd[base + j] = kd[j]; sx[base + j] = ki[j]; }
  __syncthreads();

  int cur = 0; int outIdx = 0;
#pragma unroll 1
  for (int r = 0; r < 16; r++) {
    float hv = (cur < 16) ? sd[base + cur] : __builtin_inff();
    int   hi = (cur < 16) ? sx[base + cur] : 0x7fffffff;
    int   hl = l;
#pragma unroll
    for (int m2 = 1; m2 < 64; m2 <<= 1) {
      float ov = __shfl_xor(hv, m2, 64);
      int   oi = __shfl_xor(hi, m2, 64);
      int   ol = __shfl_xor(hl, m2, 64);
      if (ov < hv || (ov == hv && oi < hi)) { hv = ov; hi = oi; hl = ol; }
    }
    if (l == hl) cur++;
    if (l == r) outIdx = hi;
  }
  if (l < 16) knnIdx[q * 16 + l] = outIdx;
}

// ---------------- gather + concat -> X0 [67][NN] ----------------
__global__ __launch_bounds__(256) void build_x0(
    const float* __restrict__ xyz, const float* __restrict__ points,
    const float* __restrict__ newXyz, const int* __restrict__ knnIdx,
    float* __restrict__ X)
{
  int n = blockIdx.x * 256 + threadIdx.x;
  int b = n >> 15;
  int q = n >> 4;
  int ip = knnIdx[n];
  const float* xb = xyz + (size_t)b * 3 * NP;
  X[(size_t)0 * NN + n] = xb[ip]          - newXyz[q * 3 + 0];
  X[(size_t)1 * NN + n] = xb[NP + ip]     - newXyz[q * 3 + 1];
  X[(size_t)2 * NN + n] = xb[2 * NP + ip] - newXyz[q * 3 + 2];
  const float* pb = points + (size_t)b * DD * NP;
#pragma unroll 8
  for (int d0 = 0; d0 < DD; d0++)
    X[(size_t)(3 + d0) * NN + n] = pb[(size_t)d0 * NP + ip];
}

// ---------------- 1x1 conv: Y[COUT][NN] = W[COUT][CIN] * X[CIN][NN] ----------------
template <int CIN, int COUT>
__global__ __launch_bounds__(256) void conv_kernel(
    const float* __restrict__ X, const float* __restrict__ W, float* __restrict__ Y)
{
  int n = blockIdx.x * 256 + threadIdx.x;
  float x[CIN];
#pragma unroll
  for (int c = 0; c < CIN; c++) x[c] = X[(size_t)c * NN + n];
#pragma unroll 1
  for (int o = 0; o < COUT; o += 4) {
    float a0 = 0.f, a1 = 0.f, a2 = 0.f, a3 = 0.f;
#pragma unroll
    for (int c = 0; c < CIN; c++) {
      float xv = x[c];
      a0 = fmaf(W[(o + 0) * CIN + c], xv, a0);
      a1 = fmaf(W[(o + 1) * CIN + c], xv, a1);
      a2 = fmaf(W[(o + 2) * CIN + c], xv, a2);
      a3 = fmaf(W[(o + 3) * CIN + c], xv, a3);
    }
    Y[(size_t)(o + 0) * NN + n] = a0;
    Y[(size_t)(o + 1) * NN + n] = a1;
    Y[(size_t)(o + 2) * NN + n] = a2;
    Y[(size_t)(o + 3) * NN + n] = a3;
  }
}

// ---------------- per-channel sum / sumsq ----------------
__global__ __launch_bounds__(256) void stats_kernel(
    const float* __restrict__ Y, float* __restrict__ stats)
{
  int c = blockIdx.y;
  int base = blockIdx.x * 4096 + threadIdx.x;
  const float* yc = Y + (size_t)c * NN;
  float s1 = 0.f, s2 = 0.f;
#pragma unroll
  for (int j = 0; j < 16; j++) {
    float v = yc[base + j * 256];
    s1 += v; s2 = fmaf(v, v, s2);
  }
#pragma unroll
  for (int m = 1; m < 64; m <<= 1) {
    s1 += __shfl_xor(s1, m, 64);
    s2 += __shfl_xor(s2, m, 64);
  }
  __shared__ float r1[4], r2[4];
  int w = threadIdx.x >> 6;
  if ((threadIdx.x & 63) == 0) { r1[w] = s1; r2[w] = s2; }
  __syncthreads();
  if (threadIdx.x == 0) {
    float t1 = r1[0] + r1[1] + r1[2] + r1[3];
    float t2 = r2[0] + r2[1] + r2[2] + r2[3];
    atomicAdd(&stats[c * 2], t1);
    atomicAdd(&stats[c * 2 + 1], t2);
  }
}

// ---------------- BN(train) + LeakyReLU, in place ----------------
__global__ __launch_bounds__(256) void bn_lrelu_kernel(
    float* __restrict__ Y, const float* __restrict__ stats,
    const float* __restrict__ g, const float* __restrict__ bt)
{
  int c = blockIdx.y;
  int n = blockIdx.x * 256 + threadIdx.x;
  float mean = stats[c * 2] * (1.0f / NN);
  float var  = stats[c * 2 + 1] * (1.0f / NN) - mean * mean;
  float inv  = rsqrtf(var + 1e-5f);
  float gamma = g[c], beta = bt[c];
  size_t o = (size_t)c * NN + n;
  float v = (Y[o] - mean) * inv;
  v = v * gamma + beta;
  Y[o] = v > 0.0f ? v : 0.1f * v;
}

// ---------------- max over K=16 -> feat [B,128,S] ----------------
__global__ __launch_bounds__(256) void maxk_kernel(
    const float* __restrict__ X, float* __restrict__ out)
{
  int m = blockIdx.x * 256 + threadIdx.x;
  int s = m & 2047;
  int o = (m >> 11) & 127;
  int b = m >> 18;
  const float4* p = (const float4*)(X + (size_t)o * NN + ((size_t)((b << 11) + s) << 4));
  float4 v0 = p[0], v1 = p[1], v2 = p[2], v3 = p[3];
  float mx = fmaxf(fmaxf(fmaxf(v0.x, v0.y), fmaxf(v0.z, v0.w)),
                   fmaxf(fmaxf(v1.x, v1.y), fmaxf(v1.z, v1.w)));
  mx = fmaxf(mx, fmaxf(fmaxf(fmaxf(v2.x, v2.y), fmaxf(v2.z, v2.w)),
                       fmaxf(fmaxf(v3.x, v3.y), fmaxf(v3.z, v3.w))));
  out[24576 + (size_t)((b << 7) + o) * SS + s] = mx;
}

extern "C" void kernel_launch(void* const* d_in, const int* in_sizes, int n_in,
                              void* d_out, int out_size, void* d_ws, size_t ws_size,
                              hipStream_t stream) {
  const float* xyz    = (const float*)d_in[0];
  const float* points = (const float*)d_in[1];
  const float* w0 = (const float*)d_in[2];
  const float* w1 = (const float*)d_in[3];
  const float* w2 = (const float*)d_in[4];
  const float* g0 = (const float*)d_in[5];
  const float* b0 = (const float*)d_in[6];
  const float* g1 = (const float*)d_in[7];
  const float* b1 = (const float*)d_in[8];
  const float* g2 = (const float*)d_in[9];
  const float* b2 = (const float*)d_in[10];
  float* out = (float*)d_out;

  float* wsf    = (float*)d_ws;
  float* newXyz = wsf;                       // 24576 floats  [q*3+c]
  int*   knnIdx = (int*)(wsf + 24576);       // 131072 ints
  float* stats  = wsf + 155648;              // 256 floats
  float* Xa     = wsf + 155904;              // 67*131072
  float* Xb     = wsf + 8937728;             // 128*131072

  fps_kernel<<<BB, 512, 0, stream>>>(xyz, newXyz, out);
  knn_kernel<<<SS * BB / 4, 256, 0, stream>>>(xyz, newXyz, knnIdx);
  build_x0<<<NN / 256, 256, 0, stream>>>(xyz, points, newXyz, knnIdx, Xa);

  hipMemsetAsync(stats, 0, 256 * 4, stream);
  conv_kernel<67, 64><<<NN / 256, 256, 0, stream>>>(Xa, w0, Xb);
  stats_kernel<<<dim3(32, 64), 256, 0, stream>>>(Xb, stats);
  bn_lrelu_kernel<<<dim3(NN / 256, 64), 256, 0, stream>>>(Xb, stats, g0, b0);

  hipMemsetAsync(stats, 0, 256 * 4, stream);
  conv_kernel<64, 64><<<NN / 256, 256, 0, stream>>>(Xb, w1, Xa);
  stats_kernel<<<dim3(32, 64), 256, 0, stream>>>(Xa, stats);
  bn_lrelu_kernel<<<dim3(NN / 256, 64), 256, 0, stream>>>(Xa, stats, g1, b1);

  hipMemsetAsync(stats, 0, 256 * 4, stream);
  conv_kernel<64, 128><<<NN / 256, 256, 0, stream>>>(Xa, w2, Xb);
  stats_kernel<<<dim3(32, 128), 256, 0, stream>>>(Xb, stats);
  bn_lrelu_kernel<<<dim3(NN / 256, 128), 256, 0, stream>>>(Xb, stats, g2, b2);

  maxk_kernel<<<(BB * 128 * SS) / 256, 256, 0, stream>>>(Xb, out);
}